// Round 3
// baseline (865.814 us; speedup 1.0000x reference)
//
#include <hip/hip_runtime.h>
#include <stdint.h>

#define D_FEAT 128
#define TOPK   128
#define KSPLIT 384            // 3 x 128 (h|h|l) . (h|l|h)
#define SCALE  4096.0f
#define SCALE2 16777216.0f    // SCALE^2 (2^24, exact)

typedef float    f32x4 __attribute__((ext_vector_type(4)));
typedef _Float16 half8 __attribute__((ext_vector_type(8)));

// ---------------- squared norms (unscaled f32) ----------------
__global__ __launch_bounds__(256) void sqnorm_kernel(const float* __restrict__ X,
                                                     float* __restrict__ out, int rows) {
    int r = blockIdx.x * 256 + threadIdx.x;
    if (r >= rows) return;
    const float4* p = (const float4*)(X + (size_t)r * D_FEAT);
    float s = 0.f;
    #pragma unroll
    for (int i = 0; i < D_FEAT / 4; ++i) {
        float4 v = p[i];
        s += v.x * v.x + v.y * v.y + v.z * v.z + v.w * v.w;
    }
    out[r] = s;
}

// ---------------- f32 -> scaled f16 (hi,lo) split, K-concatenated ----------------
// A' row = [h(128) | h(128) | l(128)]   (isA = 1)
// B' row = [h(128) | l(128) | h(128)]   (isA = 0)
__global__ __launch_bounds__(128) void split_kernel(const float* __restrict__ X,
                                                    unsigned short* __restrict__ out,
                                                    int isA) {
    int row = blockIdx.x;
    int k   = threadIdx.x;
    float a = X[(size_t)row * D_FEAT + k] * SCALE;
    _Float16 h = (_Float16)a;
    float hf = (float)h;
    _Float16 l = (_Float16)(a - hf);
    unsigned short hu, lu;
    __builtin_memcpy(&hu, &h, 2);
    __builtin_memcpy(&lu, &l, 2);
    size_t b = (size_t)row * KSPLIT;
    out[b + k]              = hu;
    out[b + D_FEAT + k]     = isA ? hu : lu;
    out[b + 2 * D_FEAT + k] = isA ? lu : hu;
}

// ---------------- MFMA distance kernel -> 16-bit keys ----------------
// C = A'.B'^T (NT gemm, K=384). 128x128 tile, 4 waves of 64x64, BK=64 slabs.
// LDS chunk-XOR swizzle (T2): chunk c of row r stored at c ^ (r&7).
#define BM 128
#define BN 128
#define BKS 64
#define NSLAB (KSPLIT / BKS)   // 6

static __device__ __forceinline__ half8 lds_read_half8(const unsigned short* p) {
    half8 r;
    __builtin_memcpy(&r, p, 16);
    return r;
}

__global__ __launch_bounds__(256) void dist_mfma_kernel(
        const unsigned short* __restrict__ Asp,   // [n][384]
        const unsigned short* __restrict__ Bsp,   // [N][384]
        const float* __restrict__ x2,
        const float* __restrict__ y2,
        unsigned short* __restrict__ keyout,      // [chunk][N]
        int q0, int N) {
    __shared__ unsigned short sh[2 * BM * BKS];   // 32 KB: A then B
    unsigned short* Ash = sh;
    unsigned short* Bsh = sh + BM * BKS;

    const int tid  = threadIdx.x;
    const int lane = tid & 63;
    const int wid  = tid >> 6;
    const int wr   = wid >> 1, wc = wid & 1;
    const int mb   = blockIdx.y * BM;     // chunk-local query base
    const int nb   = blockIdx.x * BN;

    const int srow = tid >> 3;            // 0..31, staging row within 32-row group
    const int sc   = tid & 7;             // 16B chunk column 0..7

    f32x4 acc[4][4];
    #pragma unroll
    for (int i = 0; i < 4; ++i)
        #pragma unroll
        for (int j = 0; j < 4; ++j)
            acc[i][j] = (f32x4){0.f, 0.f, 0.f, 0.f};

    uint4 ra[4], rb[4];
    // prologue: load slab 0
    #pragma unroll
    for (int it = 0; it < 4; ++it) {
        int row = it * 32 + srow;
        ra[it] = *(const uint4*)(Asp + (size_t)(q0 + mb + row) * KSPLIT + sc * 8);
        rb[it] = *(const uint4*)(Bsp + (size_t)(nb + row)      * KSPLIT + sc * 8);
    }

    for (int s = 0; s < NSLAB; ++s) {
        __syncthreads();   // previous compute done reading LDS
        #pragma unroll
        for (int it = 0; it < 4; ++it) {
            int row = it * 32 + srow;
            int dst = row * 8 + (sc ^ (row & 7));
            *(uint4*)(Ash + dst * 8) = ra[it];
            *(uint4*)(Bsh + dst * 8) = rb[it];
        }
        if (s + 1 < NSLAB) {                       // prefetch next slab (in flight over MFMA)
            int kt = (s + 1) * BKS;
            #pragma unroll
            for (int it = 0; it < 4; ++it) {
                int row = it * 32 + srow;
                ra[it] = *(const uint4*)(Asp + (size_t)(q0 + mb + row) * KSPLIT + kt + sc * 8);
                rb[it] = *(const uint4*)(Bsp + (size_t)(nb + row)      * KSPLIT + kt + sc * 8);
            }
        }
        __syncthreads();   // slab visible
        #pragma unroll
        for (int kk = 0; kk < 2; ++kk) {
            half8 af[4], bf[4];
            #pragma unroll
            for (int f = 0; f < 4; ++f) {
                int m = wr * 64 + f * 16 + (lane & 15);
                int c = kk * 4 + (lane >> 4);
                af[f] = lds_read_half8(Ash + (m * 8 + (c ^ (m & 7))) * 8);
                int nn = wc * 64 + f * 16 + (lane & 15);
                bf[f] = lds_read_half8(Bsh + (nn * 8 + (c ^ (nn & 7))) * 8);
            }
            #pragma unroll
            for (int i = 0; i < 4; ++i)
                #pragma unroll
                for (int j = 0; j < 4; ++j)
                    acc[i][j] = __builtin_amdgcn_mfma_f32_16x16x32_f16(af[i], bf[j], acc[i][j], 0, 0, 0);
        }
    }

    // epilogue: key16 = bits(max(2^24*(x2+y2) - 2*S', 0)) >> 15
    float x2v[16];
    #pragma unroll
    for (int fi = 0; fi < 4; ++fi)
        #pragma unroll
        for (int r = 0; r < 4; ++r)
            x2v[fi * 4 + r] = x2[q0 + mb + wr * 64 + fi * 16 + (lane >> 4) * 4 + r];
    #pragma unroll
    for (int fj = 0; fj < 4; ++fj) {
        float yv = y2[nb + wc * 64 + fj * 16 + (lane & 15)];
        #pragma unroll
        for (int fi = 0; fi < 4; ++fi) {
            #pragma unroll
            for (int r = 0; r < 4; ++r) {
                float d = fmaf(-2.0f, acc[fi][fj][r], SCALE2 * (x2v[fi * 4 + r] + yv));
                d = fmaxf(d, 0.0f);
                int m = mb + wr * 64 + fi * 16 + (lane >> 4) * 4 + r;
                int nn = nb + wc * 64 + fj * 16 + (lane & 15);
                keyout[(size_t)m * N + nn] = (unsigned short)(__float_as_uint(d) >> 15);
            }
        }
    }
}

// ---------------- selection + vote on 16-bit keys ----------------
#define SEL_T 1024
#define VPT   64
#define NPK   32
#define CAP   4096

__global__ __launch_bounds__(SEL_T, 4) void select3_kernel(
        const unsigned short* __restrict__ keys,
        const float* __restrict__ labels,
        const float* __restrict__ Q, const float* __restrict__ Dta,
        int* __restrict__ out, int q0, int N, int n_total, int out_size) {
    const int tid = threadIdx.x;
    const unsigned short* row = keys + (size_t)blockIdx.x * N;
    const int qi = q0 + blockIdx.x;

    uint32_t pk[NPK];
    #pragma unroll
    for (int i = 0; i < 8; ++i) {
        uint4 v = *(const uint4*)(row + i * 8192 + tid * 8);
        pk[i * 4 + 0] = v.x; pk[i * 4 + 1] = v.y;
        pk[i * 4 + 2] = v.z; pk[i * 4 + 3] = v.w;
    }
    // pk[r] halves cover j = (r>>2)*8192 + tid*8 + (r&3)*2 + h

    __shared__ unsigned int red[2][SEL_T / 64];
    __shared__ unsigned int mcnt, votes_sh;
    __shared__ double       cval[CAP];
    __shared__ unsigned int ckey[CAP];

    uint32_t lo = 0, hi = 65536, base = 0;
    const int wid = tid >> 6;
    #pragma unroll
    for (int pass = 0; pass < 16; ++pass) {
        uint32_t mid = (lo + hi) >> 1;
        uint32_t cnt = 0;
        #pragma unroll
        for (int r = 0; r < NPK; ++r) {
            uint32_t p = pk[r];
            cnt += ((p & 0xFFFFu) < mid) ? 1u : 0u;
            cnt += ((p >> 16)     < mid) ? 1u : 0u;
        }
        #pragma unroll
        for (int off = 32; off > 0; off >>= 1)
            cnt += __shfl_down(cnt, off, 64);
        if ((tid & 63) == 0) red[pass & 1][wid] = cnt;
        __syncthreads();
        uint32_t tot = 0;
        #pragma unroll
        for (int w = 0; w < SEL_T / 64; ++w) tot += red[pass & 1][w];
        if (tot >= TOPK) hi = mid;
        else             { lo = mid; base = tot; }
    }
    const uint32_t tau    = lo;
    const uint32_t t_take = TOPK - base;

    if (tid == 0) { mcnt = 0; votes_sh = 0; }
    __syncthreads();

    uint32_t votes = 0;
    #pragma unroll
    for (int r = 0; r < NPK; ++r) {
        uint32_t p = pk[r];
        #pragma unroll
        for (int h = 0; h < 2; ++h) {
            uint32_t key = (h == 0) ? (p & 0xFFFFu) : (p >> 16);
            if (key <= tau) {
                int j = (r >> 2) * 8192 + tid * 8 + (r & 3) * 2 + h;
                if (key < tau) {
                    votes += (labels[j] > 0.5f) ? 1u : 0u;
                } else {
                    unsigned int lab = (labels[j] > 0.5f) ? 0x80000000u : 0u;
                    unsigned int e = atomicAdd(&mcnt, 1u);
                    if (e < CAP) {
                        // exact squared distance (f64) for reference-faithful ranking
                        const float* qp = Q   + (size_t)qi * D_FEAT;
                        const float* dp = Dta + (size_t)j  * D_FEAT;
                        double sacc = 0.0;
                        for (int k = 0; k < D_FEAT; ++k) {
                            double df = (double)qp[k] - (double)dp[k];
                            sacc = fma(df, df, sacc);
                        }
                        cval[e] = sacc;
                        ckey[e] = (unsigned int)j | lab;
                    }
                }
            }
        }
    }
    #pragma unroll
    for (int off = 32; off > 0; off >>= 1)
        votes += __shfl_down(votes, off, 64);
    if ((tid & 63) == 0 && votes) atomicAdd(&votes_sh, votes);
    __syncthreads();

    unsigned int m = mcnt; if (m > CAP) m = CAP;
    for (unsigned int e = tid; e < m; e += SEL_T) {
        double       ve = cval[e];
        unsigned int ke = ckey[e];
        unsigned int ie = ke & 0x7FFFFFFFu;
        unsigned int rank = 0;
        for (unsigned int f = 0; f < m; ++f) {
            double       vf = cval[f];
            unsigned int jf = ckey[f] & 0x7FFFFFFFu;
            rank += (vf < ve || (vf == ve && jf < ie)) ? 1u : 0u;
        }
        if (rank < t_take && (ke & 0x80000000u)) atomicAdd(&votes_sh, 1u);
    }
    __syncthreads();

    if (tid == 0) {
        unsigned int v1 = votes_sh;
        out[qi] = (v1 > TOPK / 2) ? 1 : 0;          // 64/64 tie -> class 0
        if (qi == 0 && out_size > n_total) out[n_total] = 0;
    }
}

// ---------------- host ----------------
extern "C" void kernel_launch(void* const* d_in, const int* in_sizes, int n_in,
                              void* d_out, int out_size, void* d_ws, size_t ws_size,
                              hipStream_t stream) {
    const float* Q   = (const float*)d_in[0];
    const float* Dta = (const float*)d_in[1];
    const float* L   = (const float*)d_in[2];
    const int n = in_sizes[0] / D_FEAT;    // 2048
    const int N = in_sizes[1] / D_FEAT;    // 65536
    int* out = (int*)d_out;

    char* ws = (char*)d_ws;
    size_t off = 0;
    float* y2 = (float*)(ws + off); off += (((size_t)N * 4) + 255) & ~(size_t)255;
    float* x2 = (float*)(ws + off); off += (((size_t)n * 4) + 255) & ~(size_t)255;
    unsigned short* Asp = (unsigned short*)(ws + off); off += (((size_t)n * KSPLIT * 2) + 255) & ~(size_t)255;
    unsigned short* Bsp = (unsigned short*)(ws + off); off += (((size_t)N * KSPLIT * 2) + 255) & ~(size_t)255;
    unsigned short* keybuf = (unsigned short*)(ws + off);
    size_t avail = (ws_size > off) ? (ws_size - off) : 0;

    long maxQ = (long)(avail / ((size_t)N * 2));
    int chunkQ;
    if (maxQ >= n) chunkQ = n;
    else { chunkQ = (int)((maxQ / BM) * BM); if (chunkQ < BM) chunkQ = BM; }

    sqnorm_kernel<<<dim3((N + 255) / 256), dim3(256), 0, stream>>>(Dta, y2, N);
    sqnorm_kernel<<<dim3((n + 255) / 256), dim3(256), 0, stream>>>(Q, x2, n);
    split_kernel<<<dim3(n), dim3(128), 0, stream>>>(Q, Asp, 1);
    split_kernel<<<dim3(N), dim3(128), 0, stream>>>(Dta, Bsp, 0);

    for (int q0 = 0; q0 < n; q0 += chunkQ) {
        int q = n - q0; if (q > chunkQ) q = chunkQ;
        dim3 grid(N / BN, q / BM);
        dist_mfma_kernel<<<grid, dim3(256), 0, stream>>>(Asp, Bsp, x2, y2, keybuf, q0, N);
        select3_kernel<<<dim3(q), dim3(SEL_T), 0, stream>>>(keybuf, L, Q, Dta, out, q0, N, n, out_size);
    }
}